// Round 19
// baseline (98.436 us; speedup 1.0000x reference)
//
#include <hip/hip_runtime.h>
#include <hip/hip_bf16.h>
#include <math.h>

// Sparsemax over rows of [N_ROWS, 64] fp32 — QUAD-PER-ROW (4 lanes/row,
// 16 rows/wave, 4KB LDS/wave). r19 = r18 with PLAIN stores (NT A/B):
// r18 showed occupancy 34->70% with dur unchanged (81.4 vs 82.0) — TLP not
// binding; effective HBM pinned ~4.9 TB/s while the harness's plain-store
// fill kernel hits 7.0 TB/s. NT was inherited since r9, never isolated.
// Discriminator: NT-throttled-writes -> dur drops; NT-protected-L3 ->
// FETCH jumps toward 250 GB-KB and dur rises; neutral -> ~81 (roofline).
//
// FROZEN per-value iteration arithmetic (r14: max-fold cancellation flipped
// support boundaries -> 1/rho output jumps): d = x - tau; max(d,0); (d>0).
// Michelot fixed point (z=1 simplex threshold), all decisions fp32
// (r6: fp16 flipped boundaries):
//   tau0 = max(x)-1 ; tau += (sum(max(0,x-tau))-1)/c ; stop when c fixed
//   (supports nested/shrinking; update idempotent at the fixed point).
//   reference's double -1: tau_out = tau* - 1/rho ; out = max(0, x - tau_out)

typedef float nfloat4 __attribute__((ext_vector_type(4)));

#define FOR4(OP) OP(0) OP(1) OP(2) OP(3)

__device__ __forceinline__ nfloat4 v4max(nfloat4 a, nfloat4 b) {
    nfloat4 r;
    r.x = fmaxf(a.x, b.x); r.y = fmaxf(a.y, b.y);
    r.z = fmaxf(a.z, b.z); r.w = fmaxf(a.w, b.w);
    return r;
}

__global__ __launch_bounds__(256) void sparsemax_quad_nt0(
    const float* __restrict__ x, float* __restrict__ out, long long n_rows) {
    __shared__ nfloat4 lds4[4][256];              // 4 KB per wave, wave-private
    const int lane = threadIdx.x & 63;
    const int w = threadIdx.x >> 6;
    const long long t = (long long)blockIdx.x * 4 + w;   // 16 rows per tile
    const long long row0 = t * 16;
    if (row0 >= n_rows) return;                   // whole-wave uniform exit
    nfloat4* W = lds4[w];

    const nfloat4* __restrict__ xv = reinterpret_cast<const nfloat4*>(x);
    nfloat4* __restrict__ ov = reinterpret_cast<nfloat4*>(out);
    const long long gbase = row0 * 16;            // f4 index of tile (256 f4)
    const long long f4max = n_rows * 16;
    const bool full = (row0 + 16) <= n_rows;

    // ---- stage in: global coalesced -> LDS swizzled ----
    if (full) {
#pragma unroll
        for (int i = 0; i < 4; ++i) {
            const int f = i * 64 + lane;          // linear f4 idx in tile
            const int r = f >> 4, c = f & 15;
            W[r * 16 + (c ^ (r & 7))] = xv[gbase + f];
        }
    } else {
#pragma unroll
        for (int i = 0; i < 4; ++i) {
            const int f = i * 64 + lane;
            const int r = f >> 4, c = f & 15;
            nfloat4 tv = {0.f, 0.f, 0.f, 0.f};
            if (gbase + f < f4max) tv = xv[gbase + f];
            W[r * 16 + (c ^ (r & 7))] = tv;
        }
    }
    asm volatile("" ::: "memory");   // phase order: writes before quad-reads

    const int qrow = lane >> 2;                   // tile-local row (0..15)
    const int q = lane & 3;                       // quarter within row
    const int s7 = qrow & 7;
    const int qb = qrow * 16;

    // ---- quad-read: quarter-row (16 floats) into pinned registers ----
#define QR(j) nfloat4 v##j = W[qb + ((q * 4 + j) ^ s7)];
    FOR4(QR)
#undef QR
#define PIN(j) asm volatile("" : "+v"(v##j.x), "+v"(v##j.y), "+v"(v##j.z), "+v"(v##j.w));
    FOR4(PIN)
#undef PIN

    // ---- row max (local 15 + 2-stage quad combine) -> tau0 = max - 1 ----
    nfloat4 m4 = v4max(v4max(v0, v1), v4max(v2, v3));
    float m = fmaxf(fmaxf(m4.x, m4.y), fmaxf(m4.z, m4.w));
    m = fmaxf(m, __shfl_xor(m, 1, 64));
    m = fmaxf(m, __shfl_xor(m, 2, 64));

    float tau = m - 1.0f;
    int cprev = -1;                 // force at least one iteration
    float rfin = 1.0f;
    for (int it = 0; it < 40; ++it) {
        // FROZEN per-value arithmetic: d = x - tau; max(d,0); count(d>0)
        float s0 = 0.f, s1 = 0.f;
        int c0 = 0, c1 = 0;
#define ACC(j) {                                              \
        const float d0 = v##j.x - tau, d1 = v##j.y - tau;     \
        const float d2 = v##j.z - tau, d3 = v##j.w - tau;     \
        s0 += fmaxf(d0, 0.f); c0 += (d0 > 0.f);               \
        s1 += fmaxf(d1, 0.f); c1 += (d1 > 0.f);               \
        s0 += fmaxf(d2, 0.f); c0 += (d2 > 0.f);               \
        s1 += fmaxf(d3, 0.f); c1 += (d3 > 0.f); }
        FOR4(ACC)
#undef ACC
        float s = s0 + s1;
        int c = c0 + c1;
        // quad combine: 2 DPP stages (commutative -> identical in quad)
        s += __shfl_xor(s, 1, 64);
        c += __shfl_xor(c, 1, 64);
        s += __shfl_xor(s, 2, 64);
        c += __shfl_xor(c, 2, 64);
        const bool done = (c == cprev);   // nested supports: count fixed
        cprev = c;
        const float rr = __builtin_amdgcn_rcpf((float)c);
        rfin = rr;
        tau += (s - 1.0f) * rr;           // idempotent once converged
        if (__all(done)) break;
    }
    const float tau_out = tau - rfin;     // reference double -1: tau* - 1/rho

    asm volatile("" ::: "memory");   // phase order: reads of originals below

    // ---- stage out: originals from LDS + tau via shfl -> PLAIN stores ----
    if (full) {
#pragma unroll
        for (int i = 0; i < 4; ++i) {
            const int f = i * 64 + lane;
            const int r = f >> 4, c = f & 15;
            const float tr = __shfl(tau_out, 4 * r, 64);  // lane 4r owns row r
            const nfloat4 vv = W[r * 16 + (c ^ (r & 7))];
            nfloat4 o;
            o.x = fmaxf(0.f, vv.x - tr);
            o.y = fmaxf(0.f, vv.y - tr);
            o.z = fmaxf(0.f, vv.z - tr);
            o.w = fmaxf(0.f, vv.w - tr);
            ov[gbase + f] = o;                            // plain store (A/B vs NT)
        }
    } else {
#pragma unroll
        for (int i = 0; i < 4; ++i) {
            const int f = i * 64 + lane;
            const int r = f >> 4, c = f & 15;
            const float tr = __shfl(tau_out, 4 * r, 64);
            const nfloat4 vv = W[r * 16 + (c ^ (r & 7))];
            nfloat4 o;
            o.x = fmaxf(0.f, vv.x - tr);
            o.y = fmaxf(0.f, vv.y - tr);
            o.z = fmaxf(0.f, vv.z - tr);
            o.w = fmaxf(0.f, vv.w - tr);
            if (gbase + f < f4max) ov[gbase + f] = o;     // plain store
        }
    }
}

extern "C" void kernel_launch(void* const* d_in, const int* in_sizes, int n_in,
                              void* d_out, int out_size, void* d_ws, size_t ws_size,
                              hipStream_t stream) {
    const float* x = (const float*)d_in[0];
    float* out = (float*)d_out;
    const long long n_rows = in_sizes[0] / 64;
    const long long ntiles = (n_rows + 15) / 16;

    const int block = 256;                        // 4 waves, 16KB LDS/block
    const long long grid = (ntiles + 3) / 4;      // 16384 for 1M rows
    sparsemax_quad_nt0<<<(int)grid, block, 0, stream>>>(x, out, n_rows);
}

// Round 20
// 81.777 us; speedup vs baseline: 1.2037x; 1.2037x over previous
//
#include <hip/hip_runtime.h>
#include <hip/hip_bf16.h>
#include <math.h>

// Sparsemax over rows of [N_ROWS, 64] fp32 — QUAD-PER-ROW (4 lanes/row,
// 16 rows/wave, 4KB LDS/wave), NT stores. == r18, the session's best (82.0us;
// r13 pair-per-row variant ties at 81.4us).
//
// r19 A/B PROVED the NT stores are load-bearing: plain stores = 98.4us
// (+20%) because the 268MB output stream evicts the input from the 256MB L3
// and the ~134MB of read absorption disappears. NT keeps steady HBM traffic
// at 402MB -> 4.9 TB/s effective.
//
// Falsified levers (do not retry): register residency >64 VGPR (allocator
// caps+spills, r2-r7/r16), fp16 compression (support-boundary discontinuity,
// r6), max-fold (cancellation, r14), software pipelining (r15/r16/r17),
// occupancy beyond 70% (r18: dur unchanged), plain stores (r19).
//
// FROZEN per-value iteration arithmetic: d = x - tau; max(d,0); (d>0).
// Michelot fixed point (z=1 simplex threshold), all decisions fp32:
//   tau0 = max(x)-1 ; tau += (sum(max(0,x-tau))-1)/c ; stop when c fixed
//   (supports nested/shrinking; update idempotent at the fixed point).
//   reference's double -1: tau_out = tau* - 1/rho ; out = max(0, x - tau_out)

typedef float nfloat4 __attribute__((ext_vector_type(4)));

#define FOR4(OP) OP(0) OP(1) OP(2) OP(3)

__device__ __forceinline__ nfloat4 v4max(nfloat4 a, nfloat4 b) {
    nfloat4 r;
    r.x = fmaxf(a.x, b.x); r.y = fmaxf(a.y, b.y);
    r.z = fmaxf(a.z, b.z); r.w = fmaxf(a.w, b.w);
    return r;
}

__global__ __launch_bounds__(256) void sparsemax_quad(
    const float* __restrict__ x, float* __restrict__ out, long long n_rows) {
    __shared__ nfloat4 lds4[4][256];              // 4 KB per wave, wave-private
    const int lane = threadIdx.x & 63;
    const int w = threadIdx.x >> 6;
    const long long t = (long long)blockIdx.x * 4 + w;   // 16 rows per tile
    const long long row0 = t * 16;
    if (row0 >= n_rows) return;                   // whole-wave uniform exit
    nfloat4* W = lds4[w];

    const nfloat4* __restrict__ xv = reinterpret_cast<const nfloat4*>(x);
    nfloat4* __restrict__ ov = reinterpret_cast<nfloat4*>(out);
    const long long gbase = row0 * 16;            // f4 index of tile (256 f4)
    const long long f4max = n_rows * 16;
    const bool full = (row0 + 16) <= n_rows;

    // ---- stage in: global coalesced -> LDS swizzled ----
    if (full) {
#pragma unroll
        for (int i = 0; i < 4; ++i) {
            const int f = i * 64 + lane;          // linear f4 idx in tile
            const int r = f >> 4, c = f & 15;
            W[r * 16 + (c ^ (r & 7))] = xv[gbase + f];
        }
    } else {
#pragma unroll
        for (int i = 0; i < 4; ++i) {
            const int f = i * 64 + lane;
            const int r = f >> 4, c = f & 15;
            nfloat4 tv = {0.f, 0.f, 0.f, 0.f};
            if (gbase + f < f4max) tv = xv[gbase + f];
            W[r * 16 + (c ^ (r & 7))] = tv;
        }
    }
    asm volatile("" ::: "memory");   // phase order: writes before quad-reads

    const int qrow = lane >> 2;                   // tile-local row (0..15)
    const int q = lane & 3;                       // quarter within row
    const int s7 = qrow & 7;
    const int qb = qrow * 16;

    // ---- quad-read: quarter-row (16 floats) into pinned registers ----
#define QR(j) nfloat4 v##j = W[qb + ((q * 4 + j) ^ s7)];
    FOR4(QR)
#undef QR
#define PIN(j) asm volatile("" : "+v"(v##j.x), "+v"(v##j.y), "+v"(v##j.z), "+v"(v##j.w));
    FOR4(PIN)
#undef PIN

    // ---- row max (local 15 + 2-stage quad combine) -> tau0 = max - 1 ----
    nfloat4 m4 = v4max(v4max(v0, v1), v4max(v2, v3));
    float m = fmaxf(fmaxf(m4.x, m4.y), fmaxf(m4.z, m4.w));
    m = fmaxf(m, __shfl_xor(m, 1, 64));
    m = fmaxf(m, __shfl_xor(m, 2, 64));

    float tau = m - 1.0f;
    int cprev = -1;                 // force at least one iteration
    float rfin = 1.0f;
    for (int it = 0; it < 40; ++it) {
        // FROZEN per-value arithmetic: d = x - tau; max(d,0); count(d>0)
        float s0 = 0.f, s1 = 0.f;
        int c0 = 0, c1 = 0;
#define ACC(j) {                                              \
        const float d0 = v##j.x - tau, d1 = v##j.y - tau;     \
        const float d2 = v##j.z - tau, d3 = v##j.w - tau;     \
        s0 += fmaxf(d0, 0.f); c0 += (d0 > 0.f);               \
        s1 += fmaxf(d1, 0.f); c1 += (d1 > 0.f);               \
        s0 += fmaxf(d2, 0.f); c0 += (d2 > 0.f);               \
        s1 += fmaxf(d3, 0.f); c1 += (d3 > 0.f); }
        FOR4(ACC)
#undef ACC
        float s = s0 + s1;
        int c = c0 + c1;
        // quad combine: 2 DPP stages (commutative -> identical in quad)
        s += __shfl_xor(s, 1, 64);
        c += __shfl_xor(c, 1, 64);
        s += __shfl_xor(s, 2, 64);
        c += __shfl_xor(c, 2, 64);
        const bool done = (c == cprev);   // nested supports: count fixed
        cprev = c;
        const float rr = __builtin_amdgcn_rcpf((float)c);
        rfin = rr;
        tau += (s - 1.0f) * rr;           // idempotent once converged
        if (__all(done)) break;
    }
    const float tau_out = tau - rfin;     // reference double -1: tau* - 1/rho

    asm volatile("" ::: "memory");   // phase order: reads of originals below

    // ---- stage out: originals from LDS + tau via shfl -> coalesced NT store ----
    if (full) {
#pragma unroll
        for (int i = 0; i < 4; ++i) {
            const int f = i * 64 + lane;
            const int r = f >> 4, c = f & 15;
            const float tr = __shfl(tau_out, 4 * r, 64);  // lane 4r owns row r
            const nfloat4 vv = W[r * 16 + (c ^ (r & 7))];
            nfloat4 o;
            o.x = fmaxf(0.f, vv.x - tr);
            o.y = fmaxf(0.f, vv.y - tr);
            o.z = fmaxf(0.f, vv.z - tr);
            o.w = fmaxf(0.f, vv.w - tr);
            __builtin_nontemporal_store(o, &ov[gbase + f]);
        }
    } else {
#pragma unroll
        for (int i = 0; i < 4; ++i) {
            const int f = i * 64 + lane;
            const int r = f >> 4, c = f & 15;
            const float tr = __shfl(tau_out, 4 * r, 64);
            const nfloat4 vv = W[r * 16 + (c ^ (r & 7))];
            nfloat4 o;
            o.x = fmaxf(0.f, vv.x - tr);
            o.y = fmaxf(0.f, vv.y - tr);
            o.z = fmaxf(0.f, vv.z - tr);
            o.w = fmaxf(0.f, vv.w - tr);
            if (gbase + f < f4max)
                __builtin_nontemporal_store(o, &ov[gbase + f]);
        }
    }
}

extern "C" void kernel_launch(void* const* d_in, const int* in_sizes, int n_in,
                              void* d_out, int out_size, void* d_ws, size_t ws_size,
                              hipStream_t stream) {
    const float* x = (const float*)d_in[0];
    float* out = (float*)d_out;
    const long long n_rows = in_sizes[0] / 64;
    const long long ntiles = (n_rows + 15) / 16;

    const int block = 256;                        // 4 waves, 16KB LDS/block
    const long long grid = (ntiles + 3) / 4;      // 16384 for 1M rows
    sparsemax_quad<<<(int)grid, block, 0, stream>>>(x, out, n_rows);
}